// Round 15
// baseline (335.132 us; speedup 1.0000x reference)
//
#include <hip/hip_runtime.h>
#include <hip/hip_bf16.h>

#define N_TOK 8192
#define DM    1024
#define DH    4096
#define NE    8
#define CAP   1281
#define CAPR  1408   // He row stride (11*128)
#define ISTR  1536   // idx row stride

typedef unsigned short u16;
typedef __attribute__((ext_vector_type(8))) __bf16 bf16x8;
typedef __attribute__((ext_vector_type(8))) short short8;
typedef __attribute__((ext_vector_type(4))) short s16x4;
typedef __attribute__((ext_vector_type(4))) float f4;

__device__ __forceinline__ u16 f2bf(float f){
  union { float f; unsigned u; } v; v.f = f;
  unsigned r = v.u + 0x7fffu + ((v.u >> 16) & 1u);
  return (u16)(r >> 16);
}

__device__ __forceinline__ float gelu_fast(float v){
  float u = 0.7978845608028654f * (v + 0.044715f * v * v * v);
  return v * __builtin_amdgcn_rcpf(1.0f + __expf(-2.0f * u));
}

__device__ __forceinline__ void gl2lds16(const void* g, void* l){
  __builtin_amdgcn_global_load_lds((const __attribute__((address_space(1))) void*)g,
                                   (__attribute__((address_space(3))) void*)l, 16, 0, 0);
}

// ---- 64x64 transpose-convert tile body, stride 65 (2-way banks, verified r13) ----
__device__ __forceinline__ void tcvt_tile(const float* __restrict__ ip, u16* __restrict__ op,
                                          int K, int Nn, int n0, int k0, int tt, float* tile){
  int kr = tt>>4, nc = (tt&15)*4;
  #pragma unroll
  for (int ii=0;ii<4;ii++){
    f4 v = *(const f4*)&ip[(size_t)(k0+kr+16*ii)*Nn + n0 + nc];
    float* row = &tile[(kr+16*ii)*65 + nc];
    row[0]=v[0]; row[1]=v[1]; row[2]=v[2]; row[3]=v[3];
  }
  __syncthreads();
  int nr = tt>>2, kc = (tt&3)*16;
  short8 o0, o1;
  #pragma unroll
  for (int c=0;c<8;c++){
    o0[c] = (short)f2bf(tile[(kc+c)*65 + nr]);
    o1[c] = (short)f2bf(tile[(kc+8+c)*65 + nr]);
  }
  *(short8*)&op[(size_t)(n0+nr)*K + k0 + kc] = o0;
  *(short8*)&op[(size_t)(n0+nr)*K + k0 + kc + 8] = o1;
}

// ---------- fused: router (blocks <2048) + W1 transpose (blocks >=2048) ----------
__global__ __launch_bounds__(256) void rt_k(const float* __restrict__ x, const float* __restrict__ Wr,
    const float* __restrict__ br, u16* __restrict__ Xb, int* __restrict__ top1,
    float* __restrict__ wgt, float* __restrict__ pPart,
    const float* __restrict__ W1, u16* __restrict__ W1T){
  __shared__ float shbuf[64*65];
  int bid = blockIdx.x;
  if (bid >= 2048){
    int local = bid - 2048;
    int bx = local & 63, by = (local >> 6) & 15, bz = local >> 10;
    size_t mb = (size_t)bz * (size_t)DM * (size_t)DH;
    tcvt_tile(W1 + mb, W1T + mb, DM, DH, bx*64, by*64, threadIdx.x, shbuf);
    return;
  }
  float (*pSh)[8] = (float(*)[8])shbuf;
  int wid = threadIdx.x >> 6, lane = threadIdx.x & 63;
  int n = bid * 4 + wid;
  const float* xr = x + (size_t)n * DM;
  u16* xbr = Xb + (size_t)n * DM;
  float acc[8];
  #pragma unroll
  for (int e=0;e<8;e++) acc[e]=0.f;
  #pragma unroll
  for (int c=0;c<4;c++){
    int d0 = c*256 + lane*4;
    f4 xv = *(const f4*)(xr + d0);
    s16x4 xb;
    #pragma unroll
    for (int j=0;j<4;j++) xb[j] = (short)f2bf(xv[j]);
    *(s16x4*)(xbr + d0) = xb;
    #pragma unroll
    for (int j=0;j<4;j++){
      const float* wrow = Wr + (size_t)(d0+j)*NE;
      float xs = xv[j];
      #pragma unroll
      for (int e=0;e<8;e++) acc[e] = fmaf(xs, wrow[e], acc[e]);
    }
  }
  #pragma unroll
  for (int off=32; off>0; off>>=1){
    #pragma unroll
    for (int e=0;e<8;e++) acc[e] += __shfl_down(acc[e], off, 64);
  }
  if (lane==0){
    float lg[8]; float mx = -1e30f;
    #pragma unroll
    for (int e=0;e<8;e++){ lg[e] = acc[e] + br[e]; mx = fmaxf(mx, lg[e]); }
    float p[8], s=0.f;
    #pragma unroll
    for (int e=0;e<8;e++){ p[e] = expf(lg[e]-mx); s += p[e]; }
    int bt=0; float bv=lg[0];
    #pragma unroll
    for (int e=1;e<8;e++){ if (lg[e]>bv){ bv=lg[e]; bt=e; } }
    float inv = 1.f/s;
    top1[n] = bt; wgt[n] = p[bt]*inv;
    #pragma unroll
    for (int e=0;e<8;e++) pSh[wid][e] = p[e]*inv;
  }
  __syncthreads();
  if (threadIdx.x < 8){
    int e = threadIdx.x;
    pPart[bid*8 + e] = pSh[0][e]+pSh[1][e]+pSh[2][e]+pSh[3][e];
  }
}

// ------- capacity scan (token order) + importance reduce + aux + drop-zero -------
__global__ __launch_bounds__(1024) void scan_k(const int* __restrict__ top1, int* __restrict__ idx,
    int* __restrict__ cnt, const float* __restrict__ pPart,
    float* __restrict__ y, float* __restrict__ auxOut){
  __shared__ int waveCnt[16][8];
  __shared__ int wavePre[16][8];
  __shared__ int chunkTot[8];
  __shared__ int base_s[8];
  __shared__ int dropLds[6912];
  __shared__ int nDropSh;
  __shared__ float impLds[8];
  int tid = threadIdx.x, wid = tid>>6, lane = tid&63;
  if (tid < 8){ base_s[tid] = 0; impLds[tid] = 0.f; }
  if (tid == 0) nDropSh = 0;
  __syncthreads();
  for (int c=0;c<8;c++){
    int t = c*1024 + tid;
    int e = top1[t];
    int myPre = 0;
    #pragma unroll
    for (int ex=0; ex<8; ex++){
      unsigned long long mk = __ballot(e == ex);
      if (lane == 0) waveCnt[wid][ex] = __popcll(mk);
      if (ex == e) myPre = __popcll(mk & ((1ull<<lane)-1ull));
    }
    __syncthreads();
    if (tid < 8){
      int run = 0;
      for (int wv=0; wv<16; wv++){ wavePre[wv][tid] = run; run += waveCnt[wv][tid]; }
      chunkTot[tid] = run;
    }
    __syncthreads();
    int pos = base_s[e] + wavePre[wid][e] + myPre;
    if (pos < CAP) idx[e*ISTR + pos] = t;
    else { int d = atomicAdd(&nDropSh, 1); dropLds[d] = t; }
    __syncthreads();
    if (tid < 8) base_s[tid] += chunkTot[tid];
    __syncthreads();
  }
  if (tid < 8) cnt[tid] = base_s[tid] < CAP ? base_s[tid] : CAP;
  {
    int e = tid & 7, bg = tid >> 3;
    float ps = 0.f;
    for (int b = bg; b < 2048; b += 128) ps += pPart[b*8 + e];
    atomicAdd(&impLds[e], ps);
  }
  __syncthreads();
  if (tid == 0){
    float s = 0.f;
    for (int e=0;e<8;e++) s += (impLds[e]*(1.f/N_TOK)) * ((float)base_s[e]*(1.f/N_TOK));
    *auxOut = 0.01f * 8.f * s;
  }
  int nd = nDropSh;
  for (int i=0; i<nd; i++){
    int t = dropLds[i];
    if (tid < 256){
      f4 z; z[0]=0.f; z[1]=0.f; z[2]=0.f; z[3]=0.f;
      *(f4*)&y[(size_t)t*DM + tid*4] = z;
    }
  }
}

// ======== 256x256x64 GEMM: m201-style 8-phase schedule ========
// LDS (u16): A0:0  A1:16384  B0:32768  B1:49152  (128 KiB)
// Half-tile = 128 rows x 64 cols = 2 gl2lds (pieces 2h, 2h+1).
// Iteration i (buf0 = kt 2i, buf1 = kt 2i+1), 8 phases, 1 half-tile staged/phase:
//   ph0: A1h0(kt 2i+1)  ph1: A1h1(kt 2i+1)   [buf1-A dead since prev ph7]
//   ph2: B0h0(kt 2i+2)  ph3: B0h1(kt 2i+2)+VMC(4)  [B0 dead after ph0's read]
//   ph4: A0h0(kt 2i+2)  ph5: A0h1(kt 2i+2)   [A0 dead after ph3]
//   ph6: B1h0(kt 2i+3)  ph7: B1h1(kt 2i+3)+VMC(4)  [B1 dead after ph4's read]
// VMC(4)@ph3 drains {prev ph6,7 (B1), ph0,1 (A1)} -> buf1 valid for ph4.
// VMC(4)@ph7 drains {ph2,3 (B0), ph4,5 (A0)} -> buf0 valid for next ph0.
// Per phase: ds-reads PRE-barrier (hidden under barrier wait), lgkmcnt(0) post-barrier,
// 16 MFMA under setprio(1), second barrier. (m196/m201/m233 structure.)

#define LDA(buf, m, kk) (*(const bf16x8*)&lds[(buf)*16384 + (aBase ^ ((kk)*32)) + (m)*1024])
#define LDB(buf, n, kk) (*(const bf16x8*)&lds[32768 + (buf)*16384 + (bBase ^ ((kk)*32)) + (n)*1024])

#define SA_H(buf, h, kc) do{ \
  gl2lds16(aS[2*(h)]   + (size_t)(kc)*64, &lds[(buf)*16384 + ((2*(h))*512   + t)*8]); \
  gl2lds16(aS[2*(h)+1] + (size_t)(kc)*64, &lds[(buf)*16384 + ((2*(h)+1)*512 + t)*8]); }while(0)
#define SB_H(buf, h, kc) do{ \
  gl2lds16(bS[2*(h)]   + (size_t)(kc)*64, &lds[32768 + (buf)*16384 + ((2*(h))*512   + t)*8]); \
  gl2lds16(bS[2*(h)+1] + (size_t)(kc)*64, &lds[32768 + (buf)*16384 + ((2*(h)+1)*512 + t)*8]); }while(0)

#define SB0 __builtin_amdgcn_sched_barrier(0)
#define VMC(n) asm volatile("s_waitcnt vmcnt(" #n ")" ::: "memory")

#define PHASE8(buf, q, STAGE, DOVM) do{ \
  bf16x8 a_[2][2]; \
  if ((q)==0){ \
    _Pragma("unroll") for (int n_=0;n_<4;n_++){ Bf[n_][0]=LDB(buf,n_,0); Bf[n_][1]=LDB(buf,n_,1); } \
  } \
  a_[0][0]=LDA(buf,2*(q),0);   a_[0][1]=LDA(buf,2*(q),1); \
  a_[1][0]=LDA(buf,2*(q)+1,0); a_[1][1]=LDA(buf,2*(q)+1,1); \
  STAGE; \
  SB0; \
  __builtin_amdgcn_s_barrier(); \
  asm volatile("s_waitcnt lgkmcnt(0)" ::: "memory"); \
  SB0; \
  __builtin_amdgcn_s_setprio(1); \
  _Pragma("unroll") for (int j_=0;j_<2;j_++) \
    _Pragma("unroll") for (int n_=0;n_<4;n_++) \
      _Pragma("unroll") for (int kk_=0;kk_<2;kk_++) \
        acc[2*(q)+j_][n_] = __builtin_amdgcn_mfma_f32_16x16x32_bf16(a_[j_][kk_], Bf[n_][kk_], acc[2*(q)+j_][n_], 0,0,0); \
  __builtin_amdgcn_s_setprio(0); \
  DOVM; \
  __builtin_amdgcn_s_barrier(); \
}while(0)

#define KTILE2(ii, NTv) do{ \
  int kt1 = 2*(ii)+1 < (NTv) ? 2*(ii)+1 : (NTv)-1; \
  int kt2 = 2*(ii)+2 < (NTv) ? 2*(ii)+2 : (NTv)-1; \
  int kt3 = 2*(ii)+3 < (NTv) ? 2*(ii)+3 : (NTv)-1; \
  PHASE8(0,0, SA_H(1,0,kt1), (void)0); \
  PHASE8(0,1, SA_H(1,1,kt1), (void)0); \
  PHASE8(0,2, SB_H(0,0,kt2), (void)0); \
  PHASE8(0,3, SB_H(0,1,kt2), VMC(4)); \
  PHASE8(1,0, SA_H(0,0,kt2), (void)0); \
  PHASE8(1,1, SA_H(0,1,kt2), (void)0); \
  PHASE8(1,2, SB_H(1,0,kt3), (void)0); \
  PHASE8(1,3, SB_H(1,1,kt3), VMC(4)); \
}while(0)

// Prologue: buf0 (kt0) fully + buf1's B (kt1). buf1's A staged at iter0 ph0/ph1.
#define GEMM_PROLOGUE8() do{ \
  SB_H(0,0,0); SB_H(0,1,0); \
  SA_H(0,0,0); SA_H(0,1,0); \
  SB_H(1,0,1); SB_H(1,1,1); \
  VMC(4); \
  __builtin_amdgcn_s_barrier(); }while(0)

// ---------------- GEMM1 (operand-swapped) + fused W2-transpose tail blocks ----------------
__global__ __launch_bounds__(512, 2) void gemm1_k(
    const u16* __restrict__ Xb, const u16* __restrict__ W1T,
    const float* __restrict__ b1, const int* __restrict__ idx,
    const int* __restrict__ cnt, u16* __restrict__ He,
    const float* __restrict__ W2, u16* __restrict__ W2T)
{
  __shared__ __align__(16) u16 lds[65536];
  int bid = blockIdx.x;
  int t = threadIdx.x;
  if (bid >= 768){
    int half = t >> 8, tt = t & 255;
    int tau = (bid - 768)*2 + half;
    int bx = tau & 15, by = (tau >> 4) & 63, bz = tau >> 10;
    size_t mb = (size_t)bz * (size_t)DH * (size_t)DM;
    float* tile = ((float*)lds) + half*4160;
    tcvt_tile(W2 + mb, W2T + mb, DH, DM, bx*64, by*64, tt, tile);
    return;
  }
  int x = bid & 7, k = bid >> 3;
  int g = x*16 + k/6;
  int ntS = k - (k/6)*6;
  int e = g >> 4, mtH = g & 15;
  int cn = cnt[e];
  if (ntS*256 >= cn) return;
  int lane = t&63, wid = t>>6;
  int waveM = wid>>2, waveN = wid&3;
  int rA = lane&15, kb = lane>>4, s = rA&7;

  const u16* aS[4]; const u16* bS[4];
  #pragma unroll
  for (int j=0;j<4;j++){
    int pos = j*512 + t;
    int row = pos>>3, ch = pos&7;
    int gcb = ch ^ (row&7);
    aS[j] = W1T + ((size_t)e*DH + mtH*256 + row)*DM + gcb*8;
    int slotrow = ntS*256 + row;
    int token = (slotrow < cn) ? idx[e*ISTR + slotrow] : 0;
    bS[j] = Xb + (size_t)token*DM + gcb*8;
  }
  f4 acc[8][4];
  #pragma unroll
  for (int m=0;m<8;m++)
    #pragma unroll
    for (int n=0;n<4;n++)
      #pragma unroll
      for (int j=0;j<4;j++) acc[m][n][j]=0.f;

  int aBase = (waveM*128 + rA)*64 + (kb ^ s)*8;
  int bBase = (waveN*64  + rA)*64 + (kb ^ s)*8;
  bf16x8 Bf[4][2];

  GEMM_PROLOGUE8();
  const int NT = DM/64;   // 16
  #pragma unroll 1
  for (int i=0;i<NT/2;i++){
    KTILE2(i, NT);
  }
  asm volatile("s_waitcnt vmcnt(0) lgkmcnt(0)" ::: "memory");

  int rG = lane>>4;
  #pragma unroll
  for (int m=0;m<8;m++){
    int h0 = mtH*256 + waveM*128 + m*16 + rG*4;
    f4 b4 = *(const f4*)&b1[e*DH + h0];
    #pragma unroll
    for (int n=0;n<4;n++){
      int slot = ntS*256 + waveN*64 + n*16 + rA;
      if (slot < cn){
        s16x4 v;
        #pragma unroll
        for (int j=0;j<4;j++) v[j] = (short)f2bf(gelu_fast(acc[m][n][j] + b4[j]));
        *(s16x4*)&He[((size_t)e*CAPR + slot)*DH + h0] = v;
      }
    }
  }
}

// ---------------- GEMM2: y[token] = (He @ W2 + b2) * w, scatter (256^2, 8-phase) ----------------
__global__ __launch_bounds__(512, 2) void gemm2_k(
    const u16* __restrict__ He, const u16* __restrict__ W2T,
    const float* __restrict__ b2, const int* __restrict__ idx,
    const int* __restrict__ cnt, const float* __restrict__ wgt,
    float* __restrict__ y)
{
  int bid = blockIdx.x;
  int x = bid & 7, k = bid >> 3;
  int g = x*4 + k/6;
  int mt = k - (k/6)*6;
  int e = g >> 2, nt = g & 3;
  int cn = cnt[e];
  if (mt*256 >= cn) return;
  __shared__ __align__(16) u16 lds[65536];
  int t = threadIdx.x, lane = t&63, wid = t>>6;
  int waveM = wid>>2, waveN = wid&3;
  int rA = lane&15, kb = lane>>4, s = rA&7;

  const u16* aS[4]; const u16* bS[4];
  #pragma unroll
  for (int j=0;j<4;j++){
    int pos = j*512 + t;
    int row = pos>>3, ch = pos&7;
    int gcb = ch ^ (row&7);
    int srow = mt*256 + row; if (srow >= cn) srow = cn-1;
    aS[j] = He  + ((size_t)e*CAPR + srow)*DH + gcb*8;
    bS[j] = W2T + ((size_t)e*DM + nt*256 + row)*DH + gcb*8;
  }
  f4 acc[8][4];
  #pragma unroll
  for (int m=0;m<8;m++)
    #pragma unroll
    for (int n=0;n<4;n++)
      #pragma unroll
      for (int j=0;j<4;j++) acc[m][n][j]=0.f;

  int aBase = (waveM*128 + rA)*64 + (kb ^ s)*8;
  int bBase = (waveN*64  + rA)*64 + (kb ^ s)*8;
  bf16x8 Bf[4][2];

  GEMM_PROLOGUE8();
  const int NT = DH/64;   // 64
  #pragma unroll 1
  for (int i=0;i<NT/2;i++){
    KTILE2(i, NT);
  }
  asm volatile("s_waitcnt vmcnt(0) lgkmcnt(0)" ::: "memory");

  int rG = lane>>4;
  float bias_[4];
  #pragma unroll
  for (int n=0;n<4;n++) bias_[n] = b2[e*DM + nt*256 + waveN*64 + n*16 + rA];
  #pragma unroll
  for (int m=0;m<8;m++){
    int slot0 = mt*256 + waveM*128 + m*16 + rG*4;
    #pragma unroll
    for (int j=0;j<4;j++){
      int slot = slot0 + j;
      bool valid = slot < cn;
      int tk = valid ? idx[e*ISTR + slot] : 0;
      float wv = valid ? wgt[tk] : 0.f;
      float* yr = y + (size_t)tk*DM;
      #pragma unroll
      for (int n=0;n<4;n++){
        int col = nt*256 + waveN*64 + n*16 + rA;
        if (valid) yr[col] = (acc[m][n][j] + bias_[n]) * wv;
      }
    }
  }
}

extern "C" void kernel_launch(void* const* d_in, const int* in_sizes, int n_in,
                              void* d_out, int out_size, void* d_ws, size_t ws_size,
                              hipStream_t stream){
  const float* x  = (const float*)d_in[0];
  const float* Wr = (const float*)d_in[1];
  const float* br = (const float*)d_in[2];
  const float* W1 = (const float*)d_in[3];
  const float* b1 = (const float*)d_in[4];
  const float* W2 = (const float*)d_in[5];
  const float* b2 = (const float*)d_in[6];
  float* y = (float*)d_out;

  char* ws = (char*)d_ws;
  u16* Xb  = (u16*)(ws);                                        // 16,777,216 B
  u16* W1T = (u16*)(ws + 16777216ull);                          // 67,108,864 B
  u16* W2T = (u16*)(ws + 16777216ull + 67108864ull);            // 67,108,864 B
  u16* He  = (u16*)(ws + 16777216ull + 2ull*67108864ull);       // 92,274,688 B
  char* tail = ws + 16777216ull + 2ull*67108864ull + (size_t)NE*CAPR*DH*2ull;
  int*   top1   = (int*)(tail);                                 // 32768
  float* wgt    = (float*)(tail + 32768);                       // 32768
  int*   idx    = (int*)(tail + 65536);                         // 8*1536*4 = 49152
  float* pPart  = (float*)(tail + 65536 + 49152);               // 2048*8*4 = 65536
  int*   cnt    = (int*)(tail + 65536 + 49152 + 65536);         // 32

  rt_k<<<2048 + 8192, 256, 0, stream>>>(x, Wr, br, Xb, top1, wgt, pPart, W1, W1T);
  scan_k<<<1, 1024, 0, stream>>>(top1, idx, cnt, pPart, y, y + (size_t)N_TOK*DM);
  gemm1_k<<<768 + 4096, 512, 0, stream>>>(Xb, W1T, b1, idx, cnt, He, W2, W2T);
  gemm2_k<<<192, 512, 0, stream>>>(He, W2T, b2, idx, cnt, wgt, y);

  (void)in_sizes; (void)n_in; (void)out_size; (void)ws_size;
}

// Round 16
// 328.481 us; speedup vs baseline: 1.0202x; 1.0202x over previous
//
#include <hip/hip_runtime.h>
#include <hip/hip_bf16.h>

#define N_TOK 8192
#define DM    1024
#define DH    4096
#define NE    8
#define CAP   1281
#define CAPR  1408   // He row stride (11*128)
#define ISTR  1536   // idx row stride

typedef unsigned short u16;
typedef __attribute__((ext_vector_type(8))) __bf16 bf16x8;
typedef __attribute__((ext_vector_type(8))) short short8;
typedef __attribute__((ext_vector_type(4))) short s16x4;
typedef __attribute__((ext_vector_type(4))) float f4;

__device__ __forceinline__ u16 f2bf(float f){
  union { float f; unsigned u; } v; v.f = f;
  unsigned r = v.u + 0x7fffu + ((v.u >> 16) & 1u);
  return (u16)(r >> 16);
}

__device__ __forceinline__ float gelu_fast(float v){
  float u = 0.7978845608028654f * (v + 0.044715f * v * v * v);
  return v * __builtin_amdgcn_rcpf(1.0f + __expf(-2.0f * u));
}

__device__ __forceinline__ void gl2lds16(const void* g, void* l){
  __builtin_amdgcn_global_load_lds((const __attribute__((address_space(1))) void*)g,
                                   (__attribute__((address_space(3))) void*)l, 16, 0, 0);
}

// ---- 64x64 transpose-convert tile body, stride 65 (2-way banks, verified r13) ----
__device__ __forceinline__ void tcvt_tile(const float* __restrict__ ip, u16* __restrict__ op,
                                          int K, int Nn, int n0, int k0, int tt, float* tile){
  int kr = tt>>4, nc = (tt&15)*4;
  #pragma unroll
  for (int ii=0;ii<4;ii++){
    f4 v = *(const f4*)&ip[(size_t)(k0+kr+16*ii)*Nn + n0 + nc];
    float* row = &tile[(kr+16*ii)*65 + nc];
    row[0]=v[0]; row[1]=v[1]; row[2]=v[2]; row[3]=v[3];
  }
  __syncthreads();
  int nr = tt>>2, kc = (tt&3)*16;
  short8 o0, o1;
  #pragma unroll
  for (int c=0;c<8;c++){
    o0[c] = (short)f2bf(tile[(kc+c)*65 + nr]);
    o1[c] = (short)f2bf(tile[(kc+8+c)*65 + nr]);
  }
  *(short8*)&op[(size_t)(n0+nr)*K + k0 + kc] = o0;
  *(short8*)&op[(size_t)(n0+nr)*K + k0 + kc + 8] = o1;
}

// ---------- fused: router (blocks <2048) + W1 transpose (blocks >=2048) ----------
__global__ __launch_bounds__(256) void rt_k(const float* __restrict__ x, const float* __restrict__ Wr,
    const float* __restrict__ br, u16* __restrict__ Xb, int* __restrict__ top1,
    float* __restrict__ wgt, float* __restrict__ pPart,
    const float* __restrict__ W1, u16* __restrict__ W1T){
  __shared__ float shbuf[64*65];
  int bid = blockIdx.x;
  if (bid >= 2048){
    int local = bid - 2048;
    int bx = local & 63, by = (local >> 6) & 15, bz = local >> 10;
    size_t mb = (size_t)bz * (size_t)DM * (size_t)DH;
    tcvt_tile(W1 + mb, W1T + mb, DM, DH, bx*64, by*64, threadIdx.x, shbuf);
    return;
  }
  float (*pSh)[8] = (float(*)[8])shbuf;
  int wid = threadIdx.x >> 6, lane = threadIdx.x & 63;
  int n = bid * 4 + wid;
  const float* xr = x + (size_t)n * DM;
  u16* xbr = Xb + (size_t)n * DM;
  float acc[8];
  #pragma unroll
  for (int e=0;e<8;e++) acc[e]=0.f;
  #pragma unroll
  for (int c=0;c<4;c++){
    int d0 = c*256 + lane*4;
    f4 xv = *(const f4*)(xr + d0);
    s16x4 xb;
    #pragma unroll
    for (int j=0;j<4;j++) xb[j] = (short)f2bf(xv[j]);
    *(s16x4*)(xbr + d0) = xb;
    #pragma unroll
    for (int j=0;j<4;j++){
      const float* wrow = Wr + (size_t)(d0+j)*NE;
      float xs = xv[j];
      #pragma unroll
      for (int e=0;e<8;e++) acc[e] = fmaf(xs, wrow[e], acc[e]);
    }
  }
  #pragma unroll
  for (int off=32; off>0; off>>=1){
    #pragma unroll
    for (int e=0;e<8;e++) acc[e] += __shfl_down(acc[e], off, 64);
  }
  if (lane==0){
    float lg[8]; float mx = -1e30f;
    #pragma unroll
    for (int e=0;e<8;e++){ lg[e] = acc[e] + br[e]; mx = fmaxf(mx, lg[e]); }
    float p[8], s=0.f;
    #pragma unroll
    for (int e=0;e<8;e++){ p[e] = expf(lg[e]-mx); s += p[e]; }
    int bt=0; float bv=lg[0];
    #pragma unroll
    for (int e=1;e<8;e++){ if (lg[e]>bv){ bv=lg[e]; bt=e; } }
    float inv = 1.f/s;
    top1[n] = bt; wgt[n] = p[bt]*inv;
    #pragma unroll
    for (int e=0;e<8;e++) pSh[wid][e] = p[e]*inv;
  }
  __syncthreads();
  if (threadIdx.x < 8){
    int e = threadIdx.x;
    pPart[bid*8 + e] = pSh[0][e]+pSh[1][e]+pSh[2][e]+pSh[3][e];  // plain store, no atomics
  }
}

// ------- capacity scan (token order) + importance reduce + aux + drop-zero -------
__global__ __launch_bounds__(1024) void scan_k(const int* __restrict__ top1, int* __restrict__ idx,
    int* __restrict__ cnt, const float* __restrict__ pPart,
    float* __restrict__ y, float* __restrict__ auxOut){
  __shared__ int waveCnt[16][8];
  __shared__ int wavePre[16][8];
  __shared__ int chunkTot[8];
  __shared__ int base_s[8];
  __shared__ int dropLds[6912];
  __shared__ int nDropSh;
  __shared__ float impLds[8];
  int tid = threadIdx.x, wid = tid>>6, lane = tid&63;
  if (tid < 8){ base_s[tid] = 0; impLds[tid] = 0.f; }
  if (tid == 0) nDropSh = 0;
  __syncthreads();
  for (int c=0;c<8;c++){
    int t = c*1024 + tid;
    int e = top1[t];
    int myPre = 0;
    #pragma unroll
    for (int ex=0; ex<8; ex++){
      unsigned long long mk = __ballot(e == ex);
      if (lane == 0) waveCnt[wid][ex] = __popcll(mk);
      if (ex == e) myPre = __popcll(mk & ((1ull<<lane)-1ull));
    }
    __syncthreads();
    if (tid < 8){
      int run = 0;
      for (int wv=0; wv<16; wv++){ wavePre[wv][tid] = run; run += waveCnt[wv][tid]; }
      chunkTot[tid] = run;
    }
    __syncthreads();
    int pos = base_s[e] + wavePre[wid][e] + myPre;
    if (pos < CAP) idx[e*ISTR + pos] = t;
    else { int d = atomicAdd(&nDropSh, 1); dropLds[d] = t; }
    __syncthreads();
    if (tid < 8) base_s[tid] += chunkTot[tid];
    __syncthreads();
  }
  if (tid < 8) cnt[tid] = base_s[tid] < CAP ? base_s[tid] : CAP;
  // importance reduce: pPart[2048][8]
  {
    int e = tid & 7, bg = tid >> 3;         // bg: 0..127
    float ps = 0.f;
    for (int b = bg; b < 2048; b += 128) ps += pPart[b*8 + e];
    atomicAdd(&impLds[e], ps);
  }
  __syncthreads();
  if (tid == 0){
    float s = 0.f;
    for (int e=0;e<8;e++) s += (impLds[e]*(1.f/N_TOK)) * ((float)base_s[e]*(1.f/N_TOK));
    *auxOut = 0.01f * 8.f * s;
  }
  // zero dropped rows (nDropSh ~ 0 in practice)
  int nd = nDropSh;
  for (int i=0; i<nd; i++){
    int t = dropLds[i];
    if (tid < 256){
      f4 z; z[0]=0.f; z[1]=0.f; z[2]=0.f; z[3]=0.f;
      *(f4*)&y[(size_t)t*DM + tid*4] = z;
    }
  }
}

// ======== 256x256x64 GEMM machinery (r9, verified: 0 conflicts, best known) ========
#define LDA(buf, m, kk) (*(const bf16x8*)&lds[(buf)*16384 + (aBase ^ ((kk)*32)) + (m)*1024])
#define LDB(buf, n, kk) (*(const bf16x8*)&lds[32768 + (buf)*16384 + (bBase ^ ((kk)*32)) + (n)*1024])

#define SA_J(buf, j, kc) gl2lds16(aS[j] + (size_t)(kc)*64, &lds[(buf)*16384 + ((j)*512 + t)*8])
#define SB_ALLM(buf, kc) do{ \
  gl2lds16(bS[0] + (size_t)(kc)*64, &lds[32768 + (buf)*16384 + (0*512 + t)*8]); \
  gl2lds16(bS[1] + (size_t)(kc)*64, &lds[32768 + (buf)*16384 + (1*512 + t)*8]); \
  gl2lds16(bS[2] + (size_t)(kc)*64, &lds[32768 + (buf)*16384 + (2*512 + t)*8]); \
  gl2lds16(bS[3] + (size_t)(kc)*64, &lds[32768 + (buf)*16384 + (3*512 + t)*8]); }while(0)

#define SB0 __builtin_amdgcn_sched_barrier(0)
#define LGKM(n) do{ asm volatile("s_waitcnt lgkmcnt(" #n ")" ::: "memory"); SB0; }while(0)

#define READ_A(dst, mbase, buf) do{ \
  dst[0][0]=LDA(buf,(mbase),0);   dst[0][1]=LDA(buf,(mbase),1); \
  dst[1][0]=LDA(buf,(mbase)+1,0); dst[1][1]=LDA(buf,(mbase)+1,1); }while(0)

#define MFMA_PAIR(q, A_) \
  _Pragma("unroll") for (int j_=0;j_<2;j_++) \
    _Pragma("unroll") for (int n_=0;n_<4;n_++) \
      _Pragma("unroll") for (int kk_=0;kk_<2;kk_++) \
        acc[2*(q)+j_][n_] = __builtin_amdgcn_mfma_f32_16x16x32_bf16(A_[j_][kk_], Bf[n_][kk_], acc[2*(q)+j_][n_], 0,0,0);

#define KTILE(buf, ktv, NTv) do{ \
  int kc1 = (ktv)+1 < (NTv) ? (ktv)+1 : (NTv)-1; \
  int kc2 = (ktv)+2 < (NTv) ? (ktv)+2 : (NTv)-1; \
  asm volatile("s_waitcnt vmcnt(6)" ::: "memory"); \
  __builtin_amdgcn_s_barrier(); \
  SA_J((buf)^1, 1, kc1); SA_J((buf)^1, 3, kc1); \
  _Pragma("unroll") for (int n_=0;n_<4;n_++){ Bf[n_][0] = LDB(buf,n_,0); Bf[n_][1] = LDB(buf,n_,1); } \
  READ_A(aA, 0, buf); \
  SB0; \
  READ_A(aB, 2, buf); \
  LGKM(4); \
  __builtin_amdgcn_s_setprio(1); MFMA_PAIR(0, aA); __builtin_amdgcn_s_setprio(0); \
  __builtin_amdgcn_s_barrier(); \
  SB_ALLM(buf, kc2); \
  READ_A(aA, 4, buf); \
  LGKM(4); \
  __builtin_amdgcn_s_setprio(1); MFMA_PAIR(1, aB); __builtin_amdgcn_s_setprio(0); \
  __builtin_amdgcn_s_barrier(); \
  SA_J(buf, 0, kc2); SA_J(buf, 2, kc2); \
  READ_A(aB, 6, buf); \
  LGKM(4); \
  __builtin_amdgcn_s_setprio(1); MFMA_PAIR(2, aA); __builtin_amdgcn_s_setprio(0); \
  __builtin_amdgcn_s_barrier(); \
  LGKM(0); \
  __builtin_amdgcn_s_setprio(1); MFMA_PAIR(3, aB); __builtin_amdgcn_s_setprio(0); \
}while(0)

#define GEMM_PROLOGUE() do{ \
  SB_ALLM(0, 0); \
  SA_J(0,0,0); SA_J(0,2,0); \
  SA_J(0,1,0); SA_J(0,3,0); \
  SB_ALLM(1, 1); \
  SA_J(1,0,1); SA_J(1,2,1); }while(0)

// ---------------- GEMM1 (operand-swapped) + fused W2-transpose tail blocks ----------------
__global__ __launch_bounds__(512, 2) void gemm1_k(
    const u16* __restrict__ Xb, const u16* __restrict__ W1T,
    const float* __restrict__ b1, const int* __restrict__ idx,
    const int* __restrict__ cnt, u16* __restrict__ He,
    const float* __restrict__ W2, u16* __restrict__ W2T)
{
  __shared__ __align__(16) u16 lds[65536];
  int bid = blockIdx.x;
  int t = threadIdx.x;
  if (bid >= 768){
    int half = t >> 8, tt = t & 255;
    int tau = (bid - 768)*2 + half;           // 0..8191
    int bx = tau & 15, by = (tau >> 4) & 63, bz = tau >> 10;
    size_t mb = (size_t)bz * (size_t)DH * (size_t)DM;
    float* tile = ((float*)lds) + half*4160;
    tcvt_tile(W2 + mb, W2T + mb, DH, DM, bx*64, by*64, tt, tile);
    return;
  }
  int x = bid & 7, k = bid >> 3;
  int g = x*16 + k/6;
  int ntS = k - (k/6)*6;
  int e = g >> 4, mtH = g & 15;
  int cn = cnt[e];
  if (ntS*256 >= cn) return;
  int lane = t&63, wid = t>>6;
  int waveM = wid>>2, waveN = wid&3;
  int rA = lane&15, kb = lane>>4, s = rA&7;

  const u16* aS[4]; const u16* bS[4];
  #pragma unroll
  for (int j=0;j<4;j++){
    int pos = j*512 + t;
    int row = pos>>3, ch = pos&7;
    int gcb = ch ^ (row&7);
    aS[j] = W1T + ((size_t)e*DH + mtH*256 + row)*DM + gcb*8;
    int slotrow = ntS*256 + row;
    int token = (slotrow < cn) ? idx[e*ISTR + slotrow] : 0;
    bS[j] = Xb + (size_t)token*DM + gcb*8;
  }
  f4 acc[8][4];
  #pragma unroll
  for (int m=0;m<8;m++)
    #pragma unroll
    for (int n=0;n<4;n++)
      #pragma unroll
      for (int j=0;j<4;j++) acc[m][n][j]=0.f;

  int aBase = (waveM*128 + rA)*64 + (kb ^ s)*8;
  int bBase = (waveN*64  + rA)*64 + (kb ^ s)*8;
  bf16x8 Bf[4][2], aA[2][2], aB[2][2];

  GEMM_PROLOGUE();
  const int NT = DM/64;   // 16
  #pragma unroll 1
  for (int i=0;i<NT/2;i++){
    KTILE(0, 2*i,   NT);
    KTILE(1, 2*i+1, NT);
  }
  asm volatile("s_waitcnt vmcnt(0) lgkmcnt(0)" ::: "memory");

  int rG = lane>>4;
  #pragma unroll
  for (int m=0;m<8;m++){
    int h0 = mtH*256 + waveM*128 + m*16 + rG*4;
    f4 b4 = *(const f4*)&b1[e*DH + h0];
    #pragma unroll
    for (int n=0;n<4;n++){
      int slot = ntS*256 + waveN*64 + n*16 + rA;
      if (slot < cn){
        s16x4 v;
        #pragma unroll
        for (int j=0;j<4;j++) v[j] = (short)f2bf(gelu_fast(acc[m][n][j] + b4[j]));
        *(s16x4*)&He[((size_t)e*CAPR + slot)*DH + h0] = v;
      }
    }
  }
}

// ---------------- GEMM2: y[token] = (He @ W2 + b2) * w, scatter (r9 256^2) ----------------
__global__ __launch_bounds__(512, 2) void gemm2_k(
    const u16* __restrict__ He, const u16* __restrict__ W2T,
    const float* __restrict__ b2, const int* __restrict__ idx,
    const int* __restrict__ cnt, const float* __restrict__ wgt,
    float* __restrict__ y)
{
  int bid = blockIdx.x;
  int x = bid & 7, k = bid >> 3;          // k: 0..23
  int g = x*4 + k/6;                      // g: 0..31
  int mt = k - (k/6)*6;                   // 0..5
  int e = g >> 2, nt = g & 3;
  int cn = cnt[e];
  if (mt*256 >= cn) return;
  __shared__ __align__(16) u16 lds[65536];
  int t = threadIdx.x, lane = t&63, wid = t>>6;
  int waveM = wid>>2, waveN = wid&3;
  int rA = lane&15, kb = lane>>4, s = rA&7;

  const u16* aS[4]; const u16* bS[4];
  #pragma unroll
  for (int j=0;j<4;j++){
    int pos = j*512 + t;
    int row = pos>>3, ch = pos&7;
    int gcb = ch ^ (row&7);
    int srow = mt*256 + row; if (srow >= cn) srow = cn-1;
    aS[j] = He  + ((size_t)e*CAPR + srow)*DH + gcb*8;
    bS[j] = W2T + ((size_t)e*DM + nt*256 + row)*DH + gcb*8;
  }
  f4 acc[8][4];
  #pragma unroll
  for (int m=0;m<8;m++)
    #pragma unroll
    for (int n=0;n<4;n++)
      #pragma unroll
      for (int j=0;j<4;j++) acc[m][n][j]=0.f;

  int aBase = (waveM*128 + rA)*64 + (kb ^ s)*8;
  int bBase = (waveN*64  + rA)*64 + (kb ^ s)*8;
  bf16x8 Bf[4][2], aA[2][2], aB[2][2];

  GEMM_PROLOGUE();
  const int NT = DH/64;   // 64
  #pragma unroll 1
  for (int i=0;i<NT/2;i++){
    KTILE(0, 2*i,   NT);
    KTILE(1, 2*i+1, NT);
  }
  asm volatile("s_waitcnt vmcnt(0) lgkmcnt(0)" ::: "memory");

  int rG = lane>>4;
  float bias_[4];
  #pragma unroll
  for (int n=0;n<4;n++) bias_[n] = b2[e*DM + nt*256 + waveN*64 + n*16 + rA];
  #pragma unroll
  for (int m=0;m<8;m++){
    int slot0 = mt*256 + waveM*128 + m*16 + rG*4;
    #pragma unroll
    for (int j=0;j<4;j++){
      int slot = slot0 + j;
      bool valid = slot < cn;
      int tk = valid ? idx[e*ISTR + slot] : 0;
      float wv = valid ? wgt[tk] : 0.f;
      float* yr = y + (size_t)tk*DM;
      #pragma unroll
      for (int n=0;n<4;n++){
        int col = nt*256 + waveN*64 + n*16 + rA;
        if (valid) yr[col] = (acc[m][n][j] + bias_[n]) * wv;
      }
    }
  }
}

extern "C" void kernel_launch(void* const* d_in, const int* in_sizes, int n_in,
                              void* d_out, int out_size, void* d_ws, size_t ws_size,
                              hipStream_t stream){
  const float* x  = (const float*)d_in[0];
  const float* Wr = (const float*)d_in[1];
  const float* br = (const float*)d_in[2];
  const float* W1 = (const float*)d_in[3];
  const float* b1 = (const float*)d_in[4];
  const float* W2 = (const float*)d_in[5];
  const float* b2 = (const float*)d_in[6];
  float* y = (float*)d_out;

  char* ws = (char*)d_ws;
  u16* Xb  = (u16*)(ws);                                        // 16,777,216 B
  u16* W1T = (u16*)(ws + 16777216ull);                          // 67,108,864 B
  u16* W2T = (u16*)(ws + 16777216ull + 67108864ull);            // 67,108,864 B
  u16* He  = (u16*)(ws + 16777216ull + 2ull*67108864ull);       // 92,274,688 B
  char* tail = ws + 16777216ull + 2ull*67108864ull + (size_t)NE*CAPR*DH*2ull;
  int*   top1   = (int*)(tail);                                 // 32768
  float* wgt    = (float*)(tail + 32768);                       // 32768
  int*   idx    = (int*)(tail + 65536);                         // 8*1536*4 = 49152
  float* pPart  = (float*)(tail + 65536 + 49152);               // 2048*8*4 = 65536
  int*   cnt    = (int*)(tail + 65536 + 49152 + 65536);         // 32

  rt_k<<<2048 + 8192, 256, 0, stream>>>(x, Wr, br, Xb, top1, wgt, pPart, W1, W1T);
  scan_k<<<1, 1024, 0, stream>>>(top1, idx, cnt, pPart, y, y + (size_t)N_TOK*DM);
  gemm1_k<<<768 + 4096, 512, 0, stream>>>(Xb, W1T, b1, idx, cnt, He, W2, W2T);
  gemm2_k<<<192, 512, 0, stream>>>(He, W2T, b2, idx, cnt, wgt, y);

  (void)in_sizes; (void)n_in; (void)out_size; (void)ws_size;
}